// Round 13
// baseline (68.185 us; speedup 1.0000x reference)
//
#include <hip/hip_runtime.h>

#define SQRT2F 1.41421356237309515f

typedef __attribute__((ext_vector_type(8))) short bf16x8;
typedef __attribute__((ext_vector_type(4))) float f32x4;

enum : int {
  DM_OFF   = 0,          // demod[b][o]             : 256
  BC_OFF   = 256,        // bc[o]                   : 64   (16B aligned)
  WC_OFF   = 1024,       // Wc[66][64]              : 4224 (ends 5248)
  P_OFF    = 8192,       // partials[b][64][64][2]  : 32768 (ends 40960)
  Y_OFF    = 65536,      // y[b][px][c] raw conv    : 1048576
  WS_FLOATS = Y_OFF + 1048576
};

__device__ __align__(16) float WS[WS_FLOATS];
__device__ __align__(256) unsigned bar_cnt[64];  // zero-init; returns to 0
__device__ __align__(256) unsigned bar_gen[64];  // monotonic across replays

// ---- targeted coherence: write-through / bypass at LLC, NO fences ----
__device__ __forceinline__ unsigned ld_llcu(const unsigned* p) {
  unsigned v;
  asm volatile("global_load_dword %0, %1, off sc0 sc1\n\ts_waitcnt vmcnt(0)"
               : "=v"(v) : "v"(p) : "memory");
  return v;
}
__device__ __forceinline__ float ld_llcf(const float* p) {
  float v;
  asm volatile("global_load_dword %0, %1, off sc0 sc1\n\ts_waitcnt vmcnt(0)"
               : "=v"(v) : "v"(p) : "memory");
  return v;
}
// no-wait issue; caller must execute llc_wait() before using the value
__device__ __forceinline__ void ld_llc4_nw(const float* p, f32x4& v) {
  asm volatile("global_load_dwordx4 %0, %1, off sc0 sc1"
               : "=v"(v) : "v"(p) : "memory");
}
__device__ __forceinline__ void llc_wait() {
  asm volatile("s_waitcnt vmcnt(0)" ::: "memory");
}
__device__ __forceinline__ void stg_llc1(float* p, float v) {
  asm volatile("global_store_dword %0, %1, off sc0 sc1"
               :: "v"(p), "v"(v) : "memory");
}
__device__ __forceinline__ void stg_llc4(float* p, f32x4 v) {
  asm volatile("global_store_dwordx4 %0, %1, off sc0 sc1"
               :: "v"(p), "v"(v) : "memory");
}

struct ConvSh {
  unsigned short Xl[3 * 66 * 64];   // 25344 B
  unsigned short Wl[64 * 24 * 8];   // 24576 B
  float part[512];                  //  2048 B (also sred[512])
  float s_sh[64];                   //   256 B
};
struct GoutSh {
  unsigned short ftb[128][72];      // 18432 B  bf16 feat patch (MFMA A)
  unsigned short WcTb[64][72];      //  9216 B  bf16 Wc^T (MFMA B)
  float G[100][68];                 // 27200 B  (aliased as WcL[4288] staging)
  float red[2048];                  //  8192 B
  float A[64], B[64], bcl[64];      //   768 B
};
union ShU { ConvSh c; GoutSh g; };  // 63808 B

__device__ __forceinline__ unsigned short f2bf(float v) {
  unsigned int u = __float_as_uint(v);
  u += 0x7fffu + ((u >> 16) & 1u);
  return (unsigned short)(u >> 16);
}

// ---------------------------------------------------------------------------
// mega: one launch, 256 blocks x 512 threads.
// Phase A (conv row + spread Wc + prep, LLC write-through) -> GLOBAL passive
// barrier (256 arrivals) -> Phase B (stats + bf16 MFMA G-GEMM + output).
// ---------------------------------------------------------------------------
__global__ __launch_bounds__(512) void mega_kernel(
    const float* __restrict__ x,      const float* __restrict__ scale1,
    const float* __restrict__ scale2, const float* __restrict__ shiftp,
    const float* __restrict__ mod_w,  const float* __restrict__ mod_b,
    const float* __restrict__ conv_w, const float* __restrict__ act_b,
    const float* __restrict__ b1,     const float* __restrict__ w2,
    const float* __restrict__ b2,     const float* __restrict__ w1,
    float* __restrict__ out) {
  const int bid = blockIdx.x;
  const int b = bid >> 6;
  const int r = bid & 63;
  const int t = threadIdx.x;
  const int w = t >> 6, lane = t & 63;
  const int l15 = lane & 15, l4 = lane >> 4;

  __shared__ __align__(16) ShU sh;

  // ================= Phase A: conv row r of batch b =================
  {
    const int i = t >> 3, qq = t & 7;
    const float* sv = scale1 + b * 512 + qq * 64;
    const float* mw = mod_w + i * 512 + qq * 64;
    float p = 0.f;
    for (int k = 0; k < 64; ++k) p = fmaf(sv[k], mw[k], p);
    sh.c.part[t] = p;
  }
  __syncthreads();
  if ((t & 7) == 0) {
    const int i = t >> 3;
    float s = mod_b[i];
    #pragma unroll
    for (int k = 0; k < 8; ++k) s += sh.c.part[t + k];
    sh.c.s_sh[i] = s;
  }
  __syncthreads();

  if (r == 0) {
    const int o = t >> 3, qq = t & 7;
    const float* cw = conv_w + o * 576 + qq * 72;   // 8 ich x 9 taps
    float d = 0.f;
    #pragma unroll
    for (int ii = 0; ii < 8; ++ii) {
      const float ss = sh.c.s_sh[qq * 8 + ii];
      float wsq = 0.f;
      #pragma unroll
      for (int k = 0; k < 9; ++k) { const float wv = cw[ii * 9 + k]; wsq += wv * wv; }
      d += ss * ss * wsq;
    }
    sh.c.part[t] = d;
    __syncthreads();
    if ((t & 7) == 0) {
      float dd = 1e-8f;
      #pragma unroll
      for (int k = 0; k < 8; ++k) dd += sh.c.part[t + k];
      stg_llc1(&WS[DM_OFF + b * 64 + (t >> 3)], rsqrtf(dd));
    }
    __syncthreads();
  }

  {
    int4* Xz = (int4*)sh.c.Xl;
    int4 z; z.x = z.y = z.z = z.w = 0;
    for (int idx = t; idx < 1584; idx += 512) Xz[idx] = z;
  }
  __syncthreads();

  {
    const int col = t & 63;
    const int tq = t >> 6;
    unsigned int* Xw = (unsigned int*)sh.c.Xl;
    #pragma unroll
    for (int it = 0; it < 12; ++it) {
      const int task = it * 8 + tq;          // 0..95 = row3*32 + ichpair
      const int row3 = task >> 5;
      const int ich = (task & 31) * 2;
      const int rr = r - 1 + row3;
      if (rr >= 0 && rr < 64) {
        const float* xb = x + ((size_t)(b * 64 + ich) << 12) + (rr << 6) + col;
        const float v0 = xb[0] * sh.c.s_sh[ich];
        const float v1 = xb[4096] * sh.c.s_sh[ich + 1];
        const unsigned int u = (unsigned int)f2bf(v0) | ((unsigned int)f2bf(v1) << 16);
        const int colp = col + 1;
        const int byte = ((row3 * 66 + colp) << 7) + ((((ich >> 3)) ^ (colp & 7)) << 4) + ((ich & 7) << 1);
        Xw[byte >> 2] = u;
      }
    }
  }

  const int oh = w >> 2, pg = w & 3;
  f32x4 acc[2];
  acc[0] = (f32x4){0.f, 0.f, 0.f, 0.f};
  acc[1] = (f32x4){0.f, 0.f, 0.f, 0.f};

  const bf16x8* Xv = (const bf16x8*)sh.c.Xl;
  const bf16x8* Wv = (const bf16x8*)sh.c.Wl;
  int4* Wst = (int4*)sh.c.Wl;

  for (int dy = 0; dy < 3; ++dy) {
    __syncthreads();
    #pragma unroll
    for (int i = 0; i < 3; ++i) {
      const int idx = i * 512 + t;           // 0..1535 = o*24 + dx*8 + gg
      const int o = idx / 24;
      const int g = idx - o * 24;
      const int dx = g >> 3, gg = g & 7;
      const float* cw = conv_w + o * 576 + (gg * 8) * 9 + dy * 3 + dx;
      int4 v;
      v.x = (int)((unsigned int)f2bf(cw[0])  | ((unsigned int)f2bf(cw[9])  << 16));
      v.y = (int)((unsigned int)f2bf(cw[18]) | ((unsigned int)f2bf(cw[27]) << 16));
      v.z = (int)((unsigned int)f2bf(cw[36]) | ((unsigned int)f2bf(cw[45]) << 16));
      v.w = (int)((unsigned int)f2bf(cw[54]) | ((unsigned int)f2bf(cw[63]) << 16));
      Wst[o * 24 + dx * 8 + (gg ^ (o & 7))] = v;
    }
    __syncthreads();

    #pragma unroll
    for (int dx = 0; dx < 3; ++dx) {
      #pragma unroll
      for (int kh = 0; kh < 2; ++kh) {
        const int kg = kh * 4 + l4;
        bf16x8 afr[2];
        #pragma unroll
        for (int m = 0; m < 2; ++m) {
          const int o = oh * 32 + m * 16 + l15;
          afr[m] = Wv[o * 24 + dx * 8 + (kg ^ (o & 7))];
        }
        const int colp = pg * 16 + l15 + dx;
        const bf16x8 bfr = Xv[((dy * 66 + colp) << 3) + (kg ^ (colp & 7))];
        #pragma unroll
        for (int m = 0; m < 2; ++m)
          acc[m] = __builtin_amdgcn_mfma_f32_16x16x32_bf16(
              afr[m], bfr, acc[m], 0, 0, 0);
      }
    }
  }

  {
    const int px = pg * 16 + l15;
    float* yq = WS + Y_OFF + (((size_t)b * 4096 + r * 64 + px) << 6);
    #pragma unroll
    for (int m = 0; m < 2; ++m)
      stg_llc4(yq + oh * 32 + m * 16 + l4 * 4, acc[m]);
  }

  __syncthreads();
  {
    float* sred = sh.c.part;                // [8 waves][32 o][2]
    #pragma unroll
    for (int m = 0; m < 2; ++m) {
      #pragma unroll
      for (int j = 0; j < 4; ++j) {
        float s1 = acc[m][j];
        float s2 = acc[m][j] * acc[m][j];
        #pragma unroll
        for (int off = 1; off < 16; off <<= 1) {
          s1 += __shfl_xor(s1, off);
          s2 += __shfl_xor(s2, off);
        }
        if (l15 == 0) {
          const int ol = m * 16 + l4 * 4 + j;   // 0..31
          sred[(w * 32 + ol) * 2 + 0] = s1;
          sred[(w * 32 + ol) * 2 + 1] = s2;
        }
      }
    }
    __syncthreads();
    if (t < 128) {
      const int o = t >> 1, wh = t & 1;
      const int ohh = o >> 5, ol = o & 31;
      float s = 0.f;
      #pragma unroll
      for (int pq = 0; pq < 4; ++pq)
        s += sred[(((ohh * 4 + pq) * 32) + ol) * 2 + wh];
      stg_llc1(&WS[P_OFF + (((size_t)b * 64 + r) * 64 + o) * 2 + wh], s);
    }
  }

  // ---- Wc/bc spread across all 256 blocks (17 outputs each; 17*256 = 4352)
  // placed after conv so it overlaps other blocks' barrier wait.
  if (t < 17) {
    const int idx = t * 256 + bid;            // 0..4351
    if (idx < 4224) {
      const int c = idx >> 6, o = idx & 63;
      const float* r1 = w1 + c * 256;
      float a = 0.f;
      for (int k = 0; k < 256; ++k) a = fmaf(r1[k], w2[k * 64 + o], a);
      stg_llc1(&WS[WC_OFF + idx], a);
    } else if (idx < 4288) {
      const int o = idx - 4224;
      float a = 0.f;
      for (int k = 0; k < 256; ++k) a = fmaf(b1[k], w2[k * 64 + o], a);
      stg_llc1(&WS[BC_OFF + o], a + b2[o]);
    }
  }

  // ================= GLOBAL passive barrier (no fences) =================
  asm volatile("s_waitcnt vmcnt(0)" ::: "memory");
  __syncthreads();
  if (t == 0) {
    unsigned* cnt = &bar_cnt[0];
    unsigned* gen = &bar_gen[0];
    const unsigned g0 = ld_llcu(gen);
    const unsigned old = __hip_atomic_fetch_add(cnt, 1u, __ATOMIC_RELAXED,
                                                __HIP_MEMORY_SCOPE_AGENT);
    if (old == 255u) {
      __hip_atomic_store(cnt, 0u, __ATOMIC_RELAXED, __HIP_MEMORY_SCOPE_AGENT);
      __hip_atomic_fetch_add(gen, 1u, __ATOMIC_RELAXED,
                             __HIP_MEMORY_SCOPE_AGENT);
    } else {
      while (ld_llcu(gen) == g0) __builtin_amdgcn_s_sleep(8);
    }
  }
  __syncthreads();

  // ================= Phase B: gout tile (b, ty, tx), 32x32 queries ========
  const int ty = (bid >> 3) & 7;
  const int tx = bid & 7;
  const int cy_base = ty * 8 - 1, cx_base = tx * 8 - 1;
  float* WcL = &sh.g.G[0][0];   // stage Wc+bc here before G overwrites it

  // ---- batched LLC-bypass staging: issue all 11 loads, ONE waitcnt.
  f32x4 pv0, pv1, pv2, pv3, wv0, wv1, wv2, yv[4];
  int ycell[4], ycq[4];
  bool yok[4];
  {
    const float* Pb = WS + P_OFF + (size_t)b * 8192;
    ld_llc4_nw(Pb + (size_t)t * 4, pv0);
    ld_llc4_nw(Pb + (size_t)(t + 512) * 4, pv1);
    ld_llc4_nw(Pb + (size_t)(t + 1024) * 4, pv2);
    ld_llc4_nw(Pb + (size_t)(t + 1536) * 4, pv3);
    ld_llc4_nw(WS + WC_OFF + (size_t)t * 4, wv0);
    ld_llc4_nw(WS + WC_OFF + (size_t)(t + 512) * 4, wv1);
    const int i4 = 1024 + t;
    const float* wp2 = (i4 < 1056) ? (WS + WC_OFF + (size_t)i4 * 4)
                     : (i4 < 1072) ? (WS + BC_OFF + (size_t)(i4 - 1056) * 4)
                                   : (WS + WC_OFF);
    ld_llc4_nw(wp2, wv2);
    const float* yb = WS + Y_OFF + ((size_t)b << 18);
    #pragma unroll
    for (int k = 0; k < 4; ++k) {
      const int f = t + k * 512;
      const int cell = f >> 4, cq = f & 15;
      const int li = cell / 10, lj = cell - li * 10;
      const int ciy = cy_base + li, cix = cx_base + lj;
      const bool ok = (f < 1600) && ciy >= 0 && ciy < 64 && cix >= 0 && cix < 64;
      ycell[k] = cell; ycq[k] = cq; yok[k] = ok;
      const float* ya = ok ? (yb + (((size_t)(ciy << 6) + cix) << 6) + cq * 4) : yb;
      ld_llc4_nw(ya, yv[k]);
    }
    llc_wait();
  }

  // ---- store P partial sums + WcL to LDS
  {
    const f32x4 ps = pv0 + pv1 + pv2 + pv3;
    *(f32x4*)&sh.g.red[(t >> 5) * 128 + (t & 31) * 4] = ps;
    *(f32x4*)&WcL[t * 4] = wv0;
    *(f32x4*)&WcL[(t + 512) * 4] = wv1;
    if (1024 + t < 1072) *(f32x4*)&WcL[(1024 + t) * 4] = wv2;
  }
  __syncthreads();

  // ---- rel-term Wc rows to regs; A,B coefs + bc copy (t<64); WcT bf16 build
  const int sub = t & 3, chb = sub * 16;
  float4 wa[4], wb[4];
  #pragma unroll
  for (int k = 0; k < 4; ++k) {
    wa[k] = *(const float4*)&WcL[64 * 64 + chb + k * 4];
    wb[k] = *(const float4*)&WcL[65 * 64 + chb + k * 4];
  }
  if (t < 64) {
    float S1 = 0.f, S2 = 0.f;
    #pragma unroll
    for (int m = 0; m < 16; ++m) {
      S1 += sh.g.red[m * 128 + t * 2];
      S2 += sh.g.red[m * 128 + t * 2 + 1];
    }
    const float mu = S1 * (1.f / 4096.f);
    const float var = S2 * (1.f / 4096.f) - mu * mu;
    const float dm = ld_llcf(WS + DM_OFF + b * 64 + t);
    const float rstd = rsqrtf(dm * dm * var + 1e-5f);
    const float A = dm * rstd * scale2[b * 64 + t];
    sh.g.A[t] = A;
    sh.g.B[t] = -mu * A + shiftp[b * 64 + t] + act_b[t];
    sh.g.bcl[t] = WcL[4224 + t];
  }
  {
    // WcTb[o][c] = bf16(Wc[c][o]); thread t: o = t>>3, 8 channels (t&7)*8..
    const int o = t >> 3, g = t & 7;
    int4 pk;
    unsigned int e0, e1, e2, e3;
    e0 = (unsigned int)f2bf(WcL[(g * 8 + 0) * 64 + o]) |
         ((unsigned int)f2bf(WcL[(g * 8 + 1) * 64 + o]) << 16);
    e1 = (unsigned int)f2bf(WcL[(g * 8 + 2) * 64 + o]) |
         ((unsigned int)f2bf(WcL[(g * 8 + 3) * 64 + o]) << 16);
    e2 = (unsigned int)f2bf(WcL[(g * 8 + 4) * 64 + o]) |
         ((unsigned int)f2bf(WcL[(g * 8 + 5) * 64 + o]) << 16);
    e3 = (unsigned int)f2bf(WcL[(g * 8 + 6) * 64 + o]) |
         ((unsigned int)f2bf(WcL[(g * 8 + 7) * 64 + o]) << 16);
    pk.x = (int)e0; pk.y = (int)e1; pk.z = (int)e2; pk.w = (int)e3;
    *(int4*)&sh.g.WcTb[o][g * 8] = pk;
  }
  __syncthreads();   // A,B,bcl,WcTb ready; WcL consumed

  // ---- ft: apply affine + leaky to preloaded y values -> bf16 A tile
  {
    const float4* A4 = (const float4*)sh.g.A;
    const float4* B4 = (const float4*)sh.g.B;
    #pragma unroll
    for (int k = 0; k < 4; ++k) {
      if (yok[k]) {
        const float4 Av = A4[ycq[k]], Bv = B4[ycq[k]];
        float f0, f1, f2, f3, u;
        u = yv[k][0] * Av.x + Bv.x; f0 = (u > 0.f ? u : 0.2f * u) * SQRT2F;
        u = yv[k][1] * Av.y + Bv.y; f1 = (u > 0.f ? u : 0.2f * u) * SQRT2F;
        u = yv[k][2] * Av.z + Bv.z; f2 = (u > 0.f ? u : 0.2f * u) * SQRT2F;
        u = yv[k][3] * Av.w + Bv.w; f3 = (u > 0.f ? u : 0.2f * u) * SQRT2F;
        uint2 u2;
        u2.x = (unsigned int)f2bf(f0) | ((unsigned int)f2bf(f1) << 16);
        u2.y = (unsigned int)f2bf(f2) | ((unsigned int)f2bf(f3) << 16);
        *(uint2*)&sh.g.ftb[ycell[k]][ycq[k] * 4] = u2;
      }
    }
  }
  __syncthreads();

  // ---- MFMA G-GEMM: G[cell][o] = bc[o] + ftb[cell][:] @ WcTb[o][:]
  if (w < 7) {
    bf16x8 afr[2];
    #pragma unroll
    for (int kt = 0; kt < 2; ++kt)
      afr[kt] = *(const bf16x8*)&sh.g.ftb[w * 16 + l15][kt * 32 + l4 * 8];
    #pragma unroll
    for (int n = 0; n < 4; ++n) {
      const float bcv = sh.g.bcl[n * 16 + l15];
      f32x4 gacc = (f32x4){bcv, bcv, bcv, bcv};
      #pragma unroll
      for (int kt = 0; kt < 2; ++kt) {
        const bf16x8 bfr =
            *(const bf16x8*)&sh.g.WcTb[n * 16 + l15][kt * 32 + l4 * 8];
        gacc = __builtin_amdgcn_mfma_f32_16x16x32_bf16(afr[kt], bfr, gacc, 0, 0, 0);
      }
      #pragma unroll
      for (int j = 0; j < 4; ++j) {
        const int row = w * 16 + l4 * 4 + j;
        if (row < 100) sh.g.G[row][n * 16 + l15] = gacc[j];
      }
    }
  }
  __syncthreads();

  // ---- 1024 queries, 4 threads/query, 8 passes
  const float lo = -1.f + 1e-6f, hi = 1.f - 1e-6f;
  #pragma unroll 1
  for (int pass = 0; pass < 8; ++pass) {
    const int qi = pass * 128 + (t >> 2);
    const int oy = (ty << 5) + (qi >> 5), ox = (tx << 5) + (qi & 31);

    const float cy0 = -1.f + (2.f * oy + 1.f) * (1.f / 256.f);
    const float cx0 = -1.f + (2.f * ox + 1.f) * (1.f / 256.f);

    int lcell[4];
    float area[4], rely[4], relx[4];
    int j = 0;
    #pragma unroll
    for (int vx = -1; vx <= 1; vx += 2) {
      #pragma unroll
      for (int vy = -1; vy <= 1; vy += 2) {
        float cy = cy0 + (float)vx * (1.f / 64.f) + 1e-6f;
        cy = fminf(fmaxf(cy, lo), hi);
        float cx = cx0 + (float)vy * (1.f / 64.f) + 1e-6f;
        cx = fminf(fmaxf(cx, lo), hi);
        const float fy = floorf((cy + 1.f) * 32.f);
        const float fx = floorf((cx + 1.f) * 32.f);
        const int iy = (int)fminf(fmaxf(fy, 0.f), 63.f);
        const int ix = (int)fminf(fmaxf(fx, 0.f), 63.f);
        const float qy = -1.f + (2.f * iy + 1.f) * (1.f / 64.f);
        const float qx = -1.f + (2.f * ix + 1.f) * (1.f / 64.f);
        const float ry_ = (cy0 - qy) * 64.f;
        const float rx_ = (cx0 - qx) * 64.f;
        lcell[j] = (iy - cy_base) * 10 + (ix - cx_base);
        rely[j] = ry_; relx[j] = rx_;
        area[j] = fabsf(ry_ * rx_) + 1e-9f;
        ++j;
      }
    }
    const float tot = area[0] + area[1] + area[2] + area[3];
    float wgt[4];
    #pragma unroll
    for (int k = 0; k < 4; ++k) wgt[k] = area[3 - k] / tot;   // diagonal swap
    const float swy = wgt[0] * rely[0] + wgt[1] * rely[1] + wgt[2] * rely[2] + wgt[3] * rely[3];
    const float swx = wgt[0] * relx[0] + wgt[1] * relx[1] + wgt[2] * relx[2] + wgt[3] * relx[3];

    float4 rr[4];
    #pragma unroll
    for (int k = 0; k < 4; ++k) {
      rr[k].x = swy * wa[k].x + swx * wb[k].x;
      rr[k].y = swy * wa[k].y + swx * wb[k].y;
      rr[k].z = swy * wa[k].z + swx * wb[k].z;
      rr[k].w = swy * wa[k].w + swx * wb[k].w;
    }
    #pragma unroll
    for (int jj = 0; jj < 4; ++jj) {
      const float4* gp = (const float4*)&sh.g.G[lcell[jj]][chb];
      const float wv = wgt[jj];
      #pragma unroll
      for (int k = 0; k < 4; ++k) {
        const float4 gv = gp[k];
        rr[k].x += wv * gv.x; rr[k].y += wv * gv.y;
        rr[k].z += wv * gv.z; rr[k].w += wv * gv.w;
      }
    }
    const size_t gq = ((size_t)b << 16) + (oy << 8) + ox;
    float4* op = (float4*)(out + (gq << 6) + chb);
    #pragma unroll
    for (int k = 0; k < 4; ++k) op[k] = rr[k];
  }
}

// ---------------------------------------------------------------------------
extern "C" void kernel_launch(void* const* d_in, const int* in_sizes, int n_in,
                              void* d_out, int out_size, void* d_ws, size_t ws_size,
                              hipStream_t stream) {
  (void)in_sizes; (void)n_in; (void)out_size; (void)d_ws; (void)ws_size;
  const float* x      = (const float*)d_in[0];
  const float* scale1 = (const float*)d_in[1];
  const float* scale2 = (const float*)d_in[2];
  const float* shiftp = (const float*)d_in[3];
  const float* mod_w  = (const float*)d_in[4];
  const float* mod_b  = (const float*)d_in[5];
  const float* conv_w = (const float*)d_in[6];
  const float* act_b  = (const float*)d_in[7];
  const float* w1     = (const float*)d_in[8];
  const float* b1     = (const float*)d_in[9];
  const float* w2     = (const float*)d_in[10];
  const float* b2     = (const float*)d_in[11];
  float* out = (float*)d_out;

  hipLaunchKernelGGL(mega_kernel, dim3(256), dim3(512), 0, stream,
                     x, scale1, scale2, shiftp, mod_w, mod_b, conv_w, act_b,
                     b1, w2, b2, w1, out);
}

// Round 14
// 60.837 us; speedup vs baseline: 1.1208x; 1.1208x over previous
//
#include <hip/hip_runtime.h>

#define SQRT2F 1.41421356237309515f

typedef __attribute__((ext_vector_type(8))) short bf16x8;
typedef __attribute__((ext_vector_type(4))) float f32x4;

enum : int {
  DM_OFF   = 0,          // demod[b][o]             : 256
  BC_OFF   = 256,        // bc[o]                   : 64   (16B aligned)
  WC_OFF   = 1024,       // Wc[66][64]              : 4224 (ends 5248)
  P_OFF    = 8192,       // partials[b][64][64][2]  : 32768 (ends 40960)
  WB_OFF   = 45056,      // Wbf bf16 image [3dy][1536 int4] : 18432 fl (ends 63488)
  Y_OFF    = 65536,      // y[b][px][c] raw conv    : 1048576
  WS_FLOATS = Y_OFF + 1048576
};

__device__ __align__(16) float WS[WS_FLOATS];
__device__ __align__(256) unsigned bar_cnt[4 * 64];  // per-b; returns to 0
__device__ __align__(256) unsigned bar_gen[4 * 64];  // monotonic across replays
__device__ __align__(256) unsigned bar2_cnt[64];     // Wbf barrier
__device__ __align__(256) unsigned bar2_gen[64];

// ---- targeted coherence: write-through / bypass at LLC, NO fences ----
__device__ __forceinline__ unsigned ld_llcu(const unsigned* p) {
  unsigned v;
  asm volatile("global_load_dword %0, %1, off sc0 sc1\n\ts_waitcnt vmcnt(0)"
               : "=v"(v) : "v"(p) : "memory");
  return v;
}
__device__ __forceinline__ float ld_llcf(const float* p) {
  float v;
  asm volatile("global_load_dword %0, %1, off sc0 sc1\n\ts_waitcnt vmcnt(0)"
               : "=v"(v) : "v"(p) : "memory");
  return v;
}
// no-wait issue; caller must execute llc_wait() before using the value
__device__ __forceinline__ void ld_llc4_nw(const float* p, f32x4& v) {
  asm volatile("global_load_dwordx4 %0, %1, off sc0 sc1"
               : "=v"(v) : "v"(p) : "memory");
}
__device__ __forceinline__ void llc_wait() {
  asm volatile("s_waitcnt vmcnt(0)" ::: "memory");
}
__device__ __forceinline__ void stg_llc1(float* p, float v) {
  asm volatile("global_store_dword %0, %1, off sc0 sc1"
               :: "v"(p), "v"(v) : "memory");
}
__device__ __forceinline__ void stg_llc4(float* p, f32x4 v) {
  asm volatile("global_store_dwordx4 %0, %1, off sc0 sc1"
               :: "v"(p), "v"(v) : "memory");
}

struct ConvSh {
  unsigned short Xl[3 * 66 * 64];   // 25344 B
  unsigned short Wl[64 * 24 * 8];   // 24576 B
  float part[512];                  //  2048 B (also sred[512])
  float s_sh[64];                   //   256 B
};
struct GoutSh {
  unsigned short ftb[128][72];      // 18432 B  bf16 feat patch (MFMA A)
  unsigned short WcTb[64][72];      //  9216 B  bf16 Wc^T (MFMA B)
  float G[100][68];                 // 27200 B  (aliased as WcL[4288] staging)
  float red[2048];                  //  8192 B
  float A[64], B[64], bcl[64];      //   768 B
};
union ShU { ConvSh c; GoutSh g; };  // 63808 B

__device__ __forceinline__ unsigned short f2bf(float v) {
  unsigned int u = __float_as_uint(v);
  u += 0x7fffu + ((u >> 16) & 1u);
  return (unsigned short)(u >> 16);
}

// ---------------------------------------------------------------------------
// mega: one launch, 256 blocks x 512 threads.
// Phase A: s -> coop Wbf transpose (18 int4/block) -> global barrier#2 ->
// conv row r (W staged via coalesced LLC copy) -> per-b barrier ->
// Phase B: batched staging + stats + bf16 MFMA G-GEMM + output.
// ---------------------------------------------------------------------------
__global__ __launch_bounds__(512) void mega_kernel(
    const float* __restrict__ x,      const float* __restrict__ scale1,
    const float* __restrict__ scale2, const float* __restrict__ shiftp,
    const float* __restrict__ mod_w,  const float* __restrict__ mod_b,
    const float* __restrict__ conv_w, const float* __restrict__ act_b,
    const float* __restrict__ b1,     const float* __restrict__ w2,
    const float* __restrict__ b2,     const float* __restrict__ w1,
    float* __restrict__ out) {
  const int bid = blockIdx.x;
  const int b = bid >> 6;
  const int r = bid & 63;
  const int t = threadIdx.x;
  const int w = t >> 6, lane = t & 63;
  const int l15 = lane & 15, l4 = lane >> 4;

  __shared__ __align__(16) ShU sh;

  // ================= Phase A =================
  // ---- inline s[b][*]
  {
    const int i = t >> 3, qq = t & 7;
    const float* sv = scale1 + b * 512 + qq * 64;
    const float* mw = mod_w + i * 512 + qq * 64;
    float p = 0.f;
    for (int k = 0; k < 64; ++k) p = fmaf(sv[k], mw[k], p);
    sh.c.part[t] = p;
  }
  __syncthreads();
  if ((t & 7) == 0) {
    const int i = t >> 3;
    float s = mod_b[i];
    #pragma unroll
    for (int k = 0; k < 8; ++k) s += sh.c.part[t + k];
    sh.c.s_sh[i] = s;
  }
  __syncthreads();

  // ---- coop Wbf transpose: 18 int4 slots per block (4608 = 256*18 total)
  if (t < 18) {
    const int slot = bid * 18 + t;            // dy*1536 + o*24 + dx*8 + h
    const int dy = slot / 1536;
    const int s1 = slot - dy * 1536;
    const int o = s1 / 24;
    const int g = s1 - o * 24;
    const int dx = g >> 3, h = g & 7;
    const int gg = h ^ (o & 7);
    const float* cw = conv_w + o * 576 + (gg * 8) * 9 + dy * 3 + dx;
    f32x4 v;
    const unsigned e0 = (unsigned)f2bf(cw[0])  | ((unsigned)f2bf(cw[9])  << 16);
    const unsigned e1 = (unsigned)f2bf(cw[18]) | ((unsigned)f2bf(cw[27]) << 16);
    const unsigned e2 = (unsigned)f2bf(cw[36]) | ((unsigned)f2bf(cw[45]) << 16);
    const unsigned e3 = (unsigned)f2bf(cw[54]) | ((unsigned)f2bf(cw[63]) << 16);
    v[0] = __uint_as_float(e0); v[1] = __uint_as_float(e1);
    v[2] = __uint_as_float(e2); v[3] = __uint_as_float(e3);
    stg_llc4(WS + WB_OFF + (size_t)slot * 4, v);
  }
  // ---- global barrier #2 (Wbf ready; pre-barrier work tiny & uniform)
  asm volatile("s_waitcnt vmcnt(0)" ::: "memory");
  __syncthreads();
  if (t == 0) {
    const unsigned g0 = ld_llcu(&bar2_gen[0]);
    const unsigned old = __hip_atomic_fetch_add(&bar2_cnt[0], 1u,
                          __ATOMIC_RELAXED, __HIP_MEMORY_SCOPE_AGENT);
    if (old == 255u) {
      __hip_atomic_store(&bar2_cnt[0], 0u, __ATOMIC_RELAXED,
                         __HIP_MEMORY_SCOPE_AGENT);
      __hip_atomic_fetch_add(&bar2_gen[0], 1u, __ATOMIC_RELAXED,
                             __HIP_MEMORY_SCOPE_AGENT);
    } else {
      while (ld_llcu(&bar2_gen[0]) == g0) __builtin_amdgcn_s_sleep(8);
    }
  }
  __syncthreads();

  // ---- demod (r==0; block-uniform branch)
  if (r == 0) {
    const int o = t >> 3, qq = t & 7;
    const float* cw = conv_w + o * 576 + qq * 72;   // 8 ich x 9 taps
    float d = 0.f;
    #pragma unroll
    for (int ii = 0; ii < 8; ++ii) {
      const float ss = sh.c.s_sh[qq * 8 + ii];
      float wsq = 0.f;
      #pragma unroll
      for (int k = 0; k < 9; ++k) { const float wv = cw[ii * 9 + k]; wsq += wv * wv; }
      d += ss * ss * wsq;
    }
    sh.c.part[t] = d;
    __syncthreads();
    if ((t & 7) == 0) {
      float dd = 1e-8f;
      #pragma unroll
      for (int k = 0; k < 8; ++k) dd += sh.c.part[t + k];
      stg_llc1(&WS[DM_OFF + b * 64 + (t >> 3)], rsqrtf(dd));
    }
    __syncthreads();
  }

  // ---- Wc = w1@w2 spread over r=1..8; remainder+bc on r==9 (R12 placement)
  if (r >= 1 && r <= 8) {
    const int idx = (r - 1) * 512 + t;              // 0..4095
    const int c = idx >> 6, o = idx & 63;
    const float* r1 = w1 + c * 256;
    float a = 0.f;
    for (int k = 0; k < 256; ++k) a = fmaf(r1[k], w2[k * 64 + o], a);
    stg_llc1(&WS[WC_OFF + idx], a);
  } else if (r == 9) {
    if (t < 128) {
      const int idx = 4096 + t;                     // 4096..4223
      const int c = idx >> 6, o = idx & 63;
      const float* r1 = w1 + c * 256;
      float a = 0.f;
      for (int k = 0; k < 256; ++k) a = fmaf(r1[k], w2[k * 64 + o], a);
      stg_llc1(&WS[WC_OFF + idx], a);
    } else if (t < 192) {
      const int o = t - 128;
      float a = 0.f;
      for (int k = 0; k < 256; ++k) a = fmaf(b1[k], w2[k * 64 + o], a);
      stg_llc1(&WS[BC_OFF + o], a + b2[o]);
    }
  }

  {
    int4* Xz = (int4*)sh.c.Xl;
    int4 z; z.x = z.y = z.z = z.w = 0;
    for (int idx = t; idx < 1584; idx += 512) Xz[idx] = z;
  }
  __syncthreads();

  // ---- stage x rows r-1..r+1 as bf16(x*s), XOR-swizzled
  {
    const int col = t & 63;
    const int tq = t >> 6;
    unsigned int* Xw = (unsigned int*)sh.c.Xl;
    #pragma unroll
    for (int it = 0; it < 12; ++it) {
      const int task = it * 8 + tq;          // 0..95 = row3*32 + ichpair
      const int row3 = task >> 5;
      const int ich = (task & 31) * 2;
      const int rr = r - 1 + row3;
      if (rr >= 0 && rr < 64) {
        const float* xb = x + ((size_t)(b * 64 + ich) << 12) + (rr << 6) + col;
        const float v0 = xb[0] * sh.c.s_sh[ich];
        const float v1 = xb[4096] * sh.c.s_sh[ich + 1];
        const unsigned int u = (unsigned int)f2bf(v0) | ((unsigned int)f2bf(v1) << 16);
        const int colp = col + 1;
        const int byte = ((row3 * 66 + colp) << 7) + ((((ich >> 3)) ^ (colp & 7)) << 4) + ((ich & 7) << 1);
        Xw[byte >> 2] = u;
      }
    }
  }

  const int oh = w >> 2, pg = w & 3;
  f32x4 acc[2];
  acc[0] = (f32x4){0.f, 0.f, 0.f, 0.f};
  acc[1] = (f32x4){0.f, 0.f, 0.f, 0.f};

  const bf16x8* Xv = (const bf16x8*)sh.c.Xl;
  const bf16x8* Wv = (const bf16x8*)sh.c.Wl;
  float* Wf = (float*)sh.c.Wl;

  for (int dy = 0; dy < 3; ++dy) {
    __syncthreads();
    // coalesced LLC copy of this dy's pre-transposed W slice (1536 int4)
    {
      f32x4 w0, w1v, w2v;
      const float* src = WS + WB_OFF + (size_t)dy * 6144;
      ld_llc4_nw(src + (size_t)t * 4, w0);
      ld_llc4_nw(src + (size_t)(t + 512) * 4, w1v);
      ld_llc4_nw(src + (size_t)(t + 1024) * 4, w2v);
      llc_wait();
      *(f32x4*)&Wf[(size_t)t * 4] = w0;
      *(f32x4*)&Wf[(size_t)(t + 512) * 4] = w1v;
      *(f32x4*)&Wf[(size_t)(t + 1024) * 4] = w2v;
    }
    __syncthreads();

    #pragma unroll
    for (int dx = 0; dx < 3; ++dx) {
      #pragma unroll
      for (int kh = 0; kh < 2; ++kh) {
        const int kg = kh * 4 + l4;
        bf16x8 afr[2];
        #pragma unroll
        for (int m = 0; m < 2; ++m) {
          const int o = oh * 32 + m * 16 + l15;
          afr[m] = Wv[o * 24 + dx * 8 + (kg ^ (o & 7))];
        }
        const int colp = pg * 16 + l15 + dx;
        const bf16x8 bfr = Xv[((dy * 66 + colp) << 3) + (kg ^ (colp & 7))];
        #pragma unroll
        for (int m = 0; m < 2; ++m)
          acc[m] = __builtin_amdgcn_mfma_f32_16x16x32_bf16(
              afr[m], bfr, acc[m], 0, 0, 0);
      }
    }
  }

  {
    const int px = pg * 16 + l15;
    float* yq = WS + Y_OFF + (((size_t)b * 4096 + r * 64 + px) << 6);
    #pragma unroll
    for (int m = 0; m < 2; ++m)
      stg_llc4(yq + oh * 32 + m * 16 + l4 * 4, acc[m]);
  }

  __syncthreads();
  {
    float* sred = sh.c.part;                // [8 waves][32 o][2]
    #pragma unroll
    for (int m = 0; m < 2; ++m) {
      #pragma unroll
      for (int j = 0; j < 4; ++j) {
        float s1 = acc[m][j];
        float s2 = acc[m][j] * acc[m][j];
        #pragma unroll
        for (int off = 1; off < 16; off <<= 1) {
          s1 += __shfl_xor(s1, off);
          s2 += __shfl_xor(s2, off);
        }
        if (l15 == 0) {
          const int ol = m * 16 + l4 * 4 + j;   // 0..31
          sred[(w * 32 + ol) * 2 + 0] = s1;
          sred[(w * 32 + ol) * 2 + 1] = s2;
        }
      }
    }
    __syncthreads();
    if (t < 128) {
      const int o = t >> 1, wh = t & 1;
      const int ohh = o >> 5, ol = o & 31;
      float s = 0.f;
      #pragma unroll
      for (int pq = 0; pq < 4; ++pq)
        s += sred[(((ohh * 4 + pq) * 32) + ol) * 2 + wh];
      stg_llc1(&WS[P_OFF + (((size_t)b * 64 + r) * 64 + o) * 2 + wh], s);
    }
  }

  // ================= per-b passive barrier (no fences) =================
  asm volatile("s_waitcnt vmcnt(0)" ::: "memory");
  __syncthreads();
  if (t == 0) {
    unsigned* cnt = &bar_cnt[b * 64];
    unsigned* gen = &bar_gen[b * 64];
    const unsigned g0 = ld_llcu(gen);
    const unsigned old = __hip_atomic_fetch_add(cnt, 1u, __ATOMIC_RELAXED,
                                                __HIP_MEMORY_SCOPE_AGENT);
    if (old == 63u) {
      __hip_atomic_store(cnt, 0u, __ATOMIC_RELAXED, __HIP_MEMORY_SCOPE_AGENT);
      __hip_atomic_fetch_add(gen, 1u, __ATOMIC_RELAXED,
                             __HIP_MEMORY_SCOPE_AGENT);
    } else {
      while (ld_llcu(gen) == g0) __builtin_amdgcn_s_sleep(8);
    }
  }
  __syncthreads();

  // ================= Phase B: gout tile (b, ty, tx), 32x32 queries ========
  const int ty = (bid >> 3) & 7;
  const int tx = bid & 7;
  const int cy_base = ty * 8 - 1, cx_base = tx * 8 - 1;
  float* WcL = &sh.g.G[0][0];   // stage Wc+bc here before G overwrites it

  // ---- batched LLC-bypass staging: issue all 11 loads, ONE waitcnt.
  f32x4 pv0, pv1, pv2, pv3, wv0, wv1, wv2, yv[4];
  int ycell[4], ycq[4];
  bool yok[4];
  {
    const float* Pb = WS + P_OFF + (size_t)b * 8192;
    ld_llc4_nw(Pb + (size_t)t * 4, pv0);
    ld_llc4_nw(Pb + (size_t)(t + 512) * 4, pv1);
    ld_llc4_nw(Pb + (size_t)(t + 1024) * 4, pv2);
    ld_llc4_nw(Pb + (size_t)(t + 1536) * 4, pv3);
    ld_llc4_nw(WS + WC_OFF + (size_t)t * 4, wv0);
    ld_llc4_nw(WS + WC_OFF + (size_t)(t + 512) * 4, wv1);
    const int i4 = 1024 + t;
    const float* wp2 = (i4 < 1056) ? (WS + WC_OFF + (size_t)i4 * 4)
                     : (i4 < 1072) ? (WS + BC_OFF + (size_t)(i4 - 1056) * 4)
                                   : (WS + WC_OFF);
    ld_llc4_nw(wp2, wv2);
    const float* yb = WS + Y_OFF + ((size_t)b << 18);
    #pragma unroll
    for (int k = 0; k < 4; ++k) {
      const int f = t + k * 512;
      const int cell = f >> 4, cq = f & 15;
      const int li = cell / 10, lj = cell - li * 10;
      const int ciy = cy_base + li, cix = cx_base + lj;
      const bool ok = (f < 1600) && ciy >= 0 && ciy < 64 && cix >= 0 && cix < 64;
      ycell[k] = cell; ycq[k] = cq; yok[k] = ok;
      const float* ya = ok ? (yb + (((size_t)(ciy << 6) + cix) << 6) + cq * 4) : yb;
      ld_llc4_nw(ya, yv[k]);
    }
    llc_wait();
  }

  // ---- store P partial sums + WcL to LDS
  {
    const f32x4 ps = pv0 + pv1 + pv2 + pv3;
    *(f32x4*)&sh.g.red[(t >> 5) * 128 + (t & 31) * 4] = ps;
    *(f32x4*)&WcL[t * 4] = wv0;
    *(f32x4*)&WcL[(t + 512) * 4] = wv1;
    if (1024 + t < 1072) *(f32x4*)&WcL[(1024 + t) * 4] = wv2;
  }
  __syncthreads();

  // ---- rel-term Wc rows to regs; A,B coefs + bc copy (t<64); WcT bf16 build
  const int sub = t & 3, chb = sub * 16;
  float4 wa[4], wb[4];
  #pragma unroll
  for (int k = 0; k < 4; ++k) {
    wa[k] = *(const float4*)&WcL[64 * 64 + chb + k * 4];
    wb[k] = *(const float4*)&WcL[65 * 64 + chb + k * 4];
  }
  if (t < 64) {
    float S1 = 0.f, S2 = 0.f;
    #pragma unroll
    for (int m = 0; m < 16; ++m) {
      S1 += sh.g.red[m * 128 + t * 2];
      S2 += sh.g.red[m * 128 + t * 2 + 1];
    }
    const float mu = S1 * (1.f / 4096.f);
    const float var = S2 * (1.f / 4096.f) - mu * mu;
    const float dm = ld_llcf(WS + DM_OFF + b * 64 + t);
    const float rstd = rsqrtf(dm * dm * var + 1e-5f);
    const float A = dm * rstd * scale2[b * 64 + t];
    sh.g.A[t] = A;
    sh.g.B[t] = -mu * A + shiftp[b * 64 + t] + act_b[t];
    sh.g.bcl[t] = WcL[4224 + t];
  }
  {
    // WcTb[o][c] = bf16(Wc[c][o]); thread t: o = t>>3, 8 channels (t&7)*8..
    const int o = t >> 3, g = t & 7;
    int4 pk;
    unsigned int e0, e1, e2, e3;
    e0 = (unsigned int)f2bf(WcL[(g * 8 + 0) * 64 + o]) |
         ((unsigned int)f2bf(WcL[(g * 8 + 1) * 64 + o]) << 16);
    e1 = (unsigned int)f2bf(WcL[(g * 8 + 2) * 64 + o]) |
         ((unsigned int)f2bf(WcL[(g * 8 + 3) * 64 + o]) << 16);
    e2 = (unsigned int)f2bf(WcL[(g * 8 + 4) * 64 + o]) |
         ((unsigned int)f2bf(WcL[(g * 8 + 5) * 64 + o]) << 16);
    e3 = (unsigned int)f2bf(WcL[(g * 8 + 6) * 64 + o]) |
         ((unsigned int)f2bf(WcL[(g * 8 + 7) * 64 + o]) << 16);
    pk.x = (int)e0; pk.y = (int)e1; pk.z = (int)e2; pk.w = (int)e3;
    *(int4*)&sh.g.WcTb[o][g * 8] = pk;
  }
  __syncthreads();   // A,B,bcl,WcTb ready; WcL consumed

  // ---- ft: apply affine + leaky to preloaded y values -> bf16 A tile
  {
    const float4* A4 = (const float4*)sh.g.A;
    const float4* B4 = (const float4*)sh.g.B;
    #pragma unroll
    for (int k = 0; k < 4; ++k) {
      if (yok[k]) {
        const float4 Av = A4[ycq[k]], Bv = B4[ycq[k]];
        float f0, f1, f2, f3, u;
        u = yv[k][0] * Av.x + Bv.x; f0 = (u > 0.f ? u : 0.2f * u) * SQRT2F;
        u = yv[k][1] * Av.y + Bv.y; f1 = (u > 0.f ? u : 0.2f * u) * SQRT2F;
        u = yv[k][2] * Av.z + Bv.z; f2 = (u > 0.f ? u : 0.2f * u) * SQRT2F;
        u = yv[k][3] * Av.w + Bv.w; f3 = (u > 0.f ? u : 0.2f * u) * SQRT2F;
        uint2 u2;
        u2.x = (unsigned int)f2bf(f0) | ((unsigned int)f2bf(f1) << 16);
        u2.y = (unsigned int)f2bf(f2) | ((unsigned int)f2bf(f3) << 16);
        *(uint2*)&sh.g.ftb[ycell[k]][ycq[k] * 4] = u2;
      }
    }
  }
  __syncthreads();

  // ---- MFMA G-GEMM: G[cell][o] = bc[o] + ftb[cell][:] @ WcTb[o][:]
  if (w < 7) {
    bf16x8 afr[2];
    #pragma unroll
    for (int kt = 0; kt < 2; ++kt)
      afr[kt] = *(const bf16x8*)&sh.g.ftb[w * 16 + l15][kt * 32 + l4 * 8];
    #pragma unroll
    for (int n = 0; n < 4; ++n) {
      const float bcv = sh.g.bcl[n * 16 + l15];
      f32x4 gacc = (f32x4){bcv, bcv, bcv, bcv};
      #pragma unroll
      for (int kt = 0; kt < 2; ++kt) {
        const bf16x8 bfr =
            *(const bf16x8*)&sh.g.WcTb[n * 16 + l15][kt * 32 + l4 * 8];
        gacc = __builtin_amdgcn_mfma_f32_16x16x32_bf16(afr[kt], bfr, gacc, 0, 0, 0);
      }
      #pragma unroll
      for (int j = 0; j < 4; ++j) {
        const int row = w * 16 + l4 * 4 + j;
        if (row < 100) sh.g.G[row][n * 16 + l15] = gacc[j];
      }
    }
  }
  __syncthreads();

  // ---- 1024 queries, 4 threads/query, 8 passes
  const float lo = -1.f + 1e-6f, hi = 1.f - 1e-6f;
  #pragma unroll 1
  for (int pass = 0; pass < 8; ++pass) {
    const int qi = pass * 128 + (t >> 2);
    const int oy = (ty << 5) + (qi >> 5), ox = (tx << 5) + (qi & 31);

    const float cy0 = -1.f + (2.f * oy + 1.f) * (1.f / 256.f);
    const float cx0 = -1.f + (2.f * ox + 1.f) * (1.f / 256.f);

    int lcell[4];
    float area[4], rely[4], relx[4];
    int j = 0;
    #pragma unroll
    for (int vx = -1; vx <= 1; vx += 2) {
      #pragma unroll
      for (int vy = -1; vy <= 1; vy += 2) {
        float cy = cy0 + (float)vx * (1.f / 64.f) + 1e-6f;
        cy = fminf(fmaxf(cy, lo), hi);
        float cx = cx0 + (float)vy * (1.f / 64.f) + 1e-6f;
        cx = fminf(fmaxf(cx, lo), hi);
        const float fy = floorf((cy + 1.f) * 32.f);
        const float fx = floorf((cx + 1.f) * 32.f);
        const int iy = (int)fminf(fmaxf(fy, 0.f), 63.f);
        const int ix = (int)fminf(fmaxf(fx, 0.f), 63.f);
        const float qy = -1.f + (2.f * iy + 1.f) * (1.f / 64.f);
        const float qx = -1.f + (2.f * ix + 1.f) * (1.f / 64.f);
        const float ry_ = (cy0 - qy) * 64.f;
        const float rx_ = (cx0 - qx) * 64.f;
        lcell[j] = (iy - cy_base) * 10 + (ix - cx_base);
        rely[j] = ry_; relx[j] = rx_;
        area[j] = fabsf(ry_ * rx_) + 1e-9f;
        ++j;
      }
    }
    const float tot = area[0] + area[1] + area[2] + area[3];
    float wgt[4];
    #pragma unroll
    for (int k = 0; k < 4; ++k) wgt[k] = area[3 - k] / tot;   // diagonal swap
    const float swy = wgt[0] * rely[0] + wgt[1] * rely[1] + wgt[2] * rely[2] + wgt[3] * rely[3];
    const float swx = wgt[0] * relx[0] + wgt[1] * relx[1] + wgt[2] * relx[2] + wgt[3] * relx[3];

    float4 rr[4];
    #pragma unroll
    for (int k = 0; k < 4; ++k) {
      rr[k].x = swy * wa[k].x + swx * wb[k].x;
      rr[k].y = swy * wa[k].y + swx * wb[k].y;
      rr[k].z = swy * wa[k].z + swx * wb[k].z;
      rr[k].w = swy * wa[k].w + swx * wb[k].w;
    }
    #pragma unroll
    for (int jj = 0; jj < 4; ++jj) {
      const float4* gp = (const float4*)&sh.g.G[lcell[jj]][chb];
      const float wv = wgt[jj];
      #pragma unroll
      for (int k = 0; k < 4; ++k) {
        const float4 gv = gp[k];
        rr[k].x += wv * gv.x; rr[k].y += wv * gv.y;
        rr[k].z += wv * gv.z; rr[k].w += wv * gv.w;
      }
    }
    const size_t gq = ((size_t)b << 16) + (oy << 8) + ox;
    float4* op = (float4*)(out + (gq << 6) + chb);
    #pragma unroll
    for (int k = 0; k < 4; ++k) op[k] = rr[k];
  }
}

// ---------------------------------------------------------------------------
extern "C" void kernel_launch(void* const* d_in, const int* in_sizes, int n_in,
                              void* d_out, int out_size, void* d_ws, size_t ws_size,
                              hipStream_t stream) {
  (void)in_sizes; (void)n_in; (void)out_size; (void)d_ws; (void)ws_size;
  const float* x      = (const float*)d_in[0];
  const float* scale1 = (const float*)d_in[1];
  const float* scale2 = (const float*)d_in[2];
  const float* shiftp = (const float*)d_in[3];
  const float* mod_w  = (const float*)d_in[4];
  const float* mod_b  = (const float*)d_in[5];
  const float* conv_w = (const float*)d_in[6];
  const float* act_b  = (const float*)d_in[7];
  const float* w1     = (const float*)d_in[8];
  const float* b1     = (const float*)d_in[9];
  const float* w2     = (const float*)d_in[10];
  const float* b2     = (const float*)d_in[11];
  float* out = (float*)d_out;

  hipLaunchKernelGGL(mega_kernel, dim3(256), dim3(512), 0, stream,
                     x, scale1, scale2, shiftp, mod_w, mod_b, conv_w, act_b,
                     b1, w2, b2, w1, out);
}

// Round 15
// 58.529 us; speedup vs baseline: 1.1650x; 1.0394x over previous
//
#include <hip/hip_runtime.h>

#define SQRT2F 1.41421356237309515f

typedef __attribute__((ext_vector_type(8))) short bf16x8;
typedef __attribute__((ext_vector_type(4))) float f32x4;

enum : int {
  DM_OFF   = 0,          // demod[b][o]             : 256
  BC_OFF   = 256,        // bc[o]                   : 64   (16B aligned)
  WC_OFF   = 1024,       // Wc[66][64]              : 4224 (ends 5248)
  P_OFF    = 8192,       // partials[b][64][64][2]  : 32768 (ends 40960)
  WB_OFF   = 45056,      // Wbf bf16 image [3dy][1536 int4] : 18432 fl
  Y_OFF    = 65536,      // y[b][px][c] raw conv    : 1048576
  WS_FLOATS = Y_OFF + 1048576
};

__device__ __align__(16) float WS[WS_FLOATS];
__device__ __align__(256) unsigned bar_cnt[4 * 64];  // per-b; returns to 0
__device__ __align__(256) unsigned bar_gen[4 * 64];  // monotonic across replays
__device__ __align__(256) unsigned bar2_cnt[64];     // Wbf barrier
__device__ __align__(256) unsigned bar2_gen[64];

// ---- targeted coherence: write-through / bypass at LLC, NO fences ----
__device__ __forceinline__ unsigned ld_llcu(const unsigned* p) {
  unsigned v;
  asm volatile("global_load_dword %0, %1, off sc0 sc1\n\ts_waitcnt vmcnt(0)"
               : "=v"(v) : "v"(p) : "memory");
  return v;
}
__device__ __forceinline__ float ld_llcf(const float* p) {
  float v;
  asm volatile("global_load_dword %0, %1, off sc0 sc1\n\ts_waitcnt vmcnt(0)"
               : "=v"(v) : "v"(p) : "memory");
  return v;
}
// no-wait issue; caller must execute llc_wait() before using the value
__device__ __forceinline__ void ld_llc4_nw(const float* p, f32x4& v) {
  asm volatile("global_load_dwordx4 %0, %1, off sc0 sc1"
               : "=v"(v) : "v"(p) : "memory");
}
__device__ __forceinline__ void llc_wait() {
  asm volatile("s_waitcnt vmcnt(0)" ::: "memory");
}
__device__ __forceinline__ void stg_llc1(float* p, float v) {
  asm volatile("global_store_dword %0, %1, off sc0 sc1"
               :: "v"(p), "v"(v) : "memory");
}
__device__ __forceinline__ void stg_llc4(float* p, f32x4 v) {
  asm volatile("global_store_dwordx4 %0, %1, off sc0 sc1"
               :: "v"(p), "v"(v) : "memory");
}

struct ConvSh {
  unsigned short Xl[3 * 66 * 64];   // 25344 B
  unsigned short Wl[64 * 24 * 8];   // 24576 B
  float part[512];                  //  2048 B (also sred[512])
  float s_sh[64];                   //   256 B
};
struct GoutSh {
  unsigned short ftb[128][72];      // 18432 B  bf16 feat patch (MFMA A)
  unsigned short WcTb[64][72];      //  9216 B  bf16 Wc^T (MFMA B)
  float G[100][68];                 // 27200 B  (aliased as WcL[4288] staging)
  float red[2048];                  //  8192 B
  float A[64], B[64], bcl[64];      //   768 B
};
union ShU { ConvSh c; GoutSh g; };  // 63808 B

__device__ __forceinline__ unsigned short f2bf(float v) {
  unsigned int u = __float_as_uint(v);
  u += 0x7fffu + ((u >> 16) & 1u);
  return (unsigned short)(u >> 16);
}

// ---------------------------------------------------------------------------
// mega: one launch, 256 blocks x 512 threads.
// Phase A: s -> Wbf transpose -> barrier#2 ARRIVE -> demod/Wc/X-stage
// (overlaps barrier#2 wait) -> barrier#2 WAIT -> conv (W prefetch pipelined)
// -> per-b barrier -> Phase B: batched staging + MFMA G-GEMM + output.
// ---------------------------------------------------------------------------
__global__ __launch_bounds__(512) void mega_kernel(
    const float* __restrict__ x,      const float* __restrict__ scale1,
    const float* __restrict__ scale2, const float* __restrict__ shiftp,
    const float* __restrict__ mod_w,  const float* __restrict__ mod_b,
    const float* __restrict__ conv_w, const float* __restrict__ act_b,
    const float* __restrict__ b1,     const float* __restrict__ w2,
    const float* __restrict__ b2,     const float* __restrict__ w1,
    float* __restrict__ out) {
  const int bid = blockIdx.x;
  const int b = bid >> 6;
  const int r = bid & 63;
  const int t = threadIdx.x;
  const int w = t >> 6, lane = t & 63;
  const int l15 = lane & 15, l4 = lane >> 4;

  __shared__ __align__(16) ShU sh;

  // ================= Phase A =================
  // ---- inline s[b][*]
  {
    const int i = t >> 3, qq = t & 7;
    const float* sv = scale1 + b * 512 + qq * 64;
    const float* mw = mod_w + i * 512 + qq * 64;
    float p = 0.f;
    for (int k = 0; k < 64; ++k) p = fmaf(sv[k], mw[k], p);
    sh.c.part[t] = p;
  }
  __syncthreads();
  if ((t & 7) == 0) {
    const int i = t >> 3;
    float s = mod_b[i];
    #pragma unroll
    for (int k = 0; k < 8; ++k) s += sh.c.part[t + k];
    sh.c.s_sh[i] = s;
  }
  __syncthreads();

  // ---- coop Wbf transpose: 18 int4 slots per block (4608 = 256*18 total)
  if (t < 18) {
    const int slot = bid * 18 + t;            // dy*1536 + o*24 + dx*8 + h
    const int dy = slot / 1536;
    const int s1 = slot - dy * 1536;
    const int o = s1 / 24;
    const int g = s1 - o * 24;
    const int dx = g >> 3, h = g & 7;
    const int gg = h ^ (o & 7);
    const float* cw = conv_w + o * 576 + (gg * 8) * 9 + dy * 3 + dx;
    f32x4 v;
    const unsigned e0 = (unsigned)f2bf(cw[0])  | ((unsigned)f2bf(cw[9])  << 16);
    const unsigned e1 = (unsigned)f2bf(cw[18]) | ((unsigned)f2bf(cw[27]) << 16);
    const unsigned e2 = (unsigned)f2bf(cw[36]) | ((unsigned)f2bf(cw[45]) << 16);
    const unsigned e3 = (unsigned)f2bf(cw[54]) | ((unsigned)f2bf(cw[63]) << 16);
    v[0] = __uint_as_float(e0); v[1] = __uint_as_float(e1);
    v[2] = __uint_as_float(e2); v[3] = __uint_as_float(e3);
    stg_llc4(WS + WB_OFF + (size_t)slot * 4, v);
  }
  // ---- barrier#2 ARRIVE (split): stores drained, count in; no spin yet
  llc_wait();
  __syncthreads();
  unsigned b2_g0 = 0;
  bool b2_last = false;
  if (t == 0) {
    b2_g0 = ld_llcu(&bar2_gen[0]);
    const unsigned old = __hip_atomic_fetch_add(&bar2_cnt[0], 1u,
                          __ATOMIC_RELAXED, __HIP_MEMORY_SCOPE_AGENT);
    if (old == 255u) {
      __hip_atomic_store(&bar2_cnt[0], 0u, __ATOMIC_RELAXED,
                         __HIP_MEMORY_SCOPE_AGENT);
      __hip_atomic_fetch_add(&bar2_gen[0], 1u, __ATOMIC_RELAXED,
                             __HIP_MEMORY_SCOPE_AGENT);
      b2_last = true;
    }
  }

  // ======== overlap window: demod / Wc / X staging (Wbf-independent) ======
  // ---- demod (r==0; block-uniform branch)
  if (r == 0) {
    const int o = t >> 3, qq = t & 7;
    const float* cw = conv_w + o * 576 + qq * 72;   // 8 ich x 9 taps
    float d = 0.f;
    #pragma unroll
    for (int ii = 0; ii < 8; ++ii) {
      const float ss = sh.c.s_sh[qq * 8 + ii];
      float wsq = 0.f;
      #pragma unroll
      for (int k = 0; k < 9; ++k) { const float wv = cw[ii * 9 + k]; wsq += wv * wv; }
      d += ss * ss * wsq;
    }
    sh.c.part[t] = d;
    __syncthreads();
    if ((t & 7) == 0) {
      float dd = 1e-8f;
      #pragma unroll
      for (int k = 0; k < 8; ++k) dd += sh.c.part[t + k];
      stg_llc1(&WS[DM_OFF + b * 64 + (t >> 3)], rsqrtf(dd));
    }
    __syncthreads();
  }

  // ---- Wc = w1@w2 spread over r=1..8; remainder+bc on r==9
  if (r >= 1 && r <= 8) {
    const int idx = (r - 1) * 512 + t;              // 0..4095
    const int c = idx >> 6, o = idx & 63;
    const float* r1 = w1 + c * 256;
    float a = 0.f;
    for (int k = 0; k < 256; ++k) a = fmaf(r1[k], w2[k * 64 + o], a);
    stg_llc1(&WS[WC_OFF + idx], a);
  } else if (r == 9) {
    if (t < 128) {
      const int idx = 4096 + t;                     // 4096..4223
      const int c = idx >> 6, o = idx & 63;
      const float* r1 = w1 + c * 256;
      float a = 0.f;
      for (int k = 0; k < 256; ++k) a = fmaf(r1[k], w2[k * 64 + o], a);
      stg_llc1(&WS[WC_OFF + idx], a);
    } else if (t < 192) {
      const int o = t - 128;
      float a = 0.f;
      for (int k = 0; k < 256; ++k) a = fmaf(b1[k], w2[k * 64 + o], a);
      stg_llc1(&WS[BC_OFF + o], a + b2[o]);
    }
  }

  {
    int4* Xz = (int4*)sh.c.Xl;
    int4 z; z.x = z.y = z.z = z.w = 0;
    for (int idx = t; idx < 1584; idx += 512) Xz[idx] = z;
  }
  __syncthreads();

  // ---- stage x rows r-1..r+1 as bf16(x*s), XOR-swizzled
  {
    const int col = t & 63;
    const int tq = t >> 6;
    unsigned int* Xw = (unsigned int*)sh.c.Xl;
    #pragma unroll
    for (int it = 0; it < 12; ++it) {
      const int task = it * 8 + tq;          // 0..95 = row3*32 + ichpair
      const int row3 = task >> 5;
      const int ich = (task & 31) * 2;
      const int rr = r - 1 + row3;
      if (rr >= 0 && rr < 64) {
        const float* xb = x + ((size_t)(b * 64 + ich) << 12) + (rr << 6) + col;
        const float v0 = xb[0] * sh.c.s_sh[ich];
        const float v1 = xb[4096] * sh.c.s_sh[ich + 1];
        const unsigned int u = (unsigned int)f2bf(v0) | ((unsigned int)f2bf(v1) << 16);
        const int colp = col + 1;
        const int byte = ((row3 * 66 + colp) << 7) + ((((ich >> 3)) ^ (colp & 7)) << 4) + ((ich & 7) << 1);
        Xw[byte >> 2] = u;
      }
    }
  }

  // ---- barrier#2 WAIT (spin only if not last; overlapped work done above)
  __syncthreads();
  if (t == 0 && !b2_last) {
    while (ld_llcu(&bar2_gen[0]) == b2_g0) __builtin_amdgcn_s_sleep(8);
  }
  __syncthreads();

  // ================= conv: W prefetch pipelined over dy =================
  const int oh = w >> 2, pg = w & 3;
  f32x4 acc[2];
  acc[0] = (f32x4){0.f, 0.f, 0.f, 0.f};
  acc[1] = (f32x4){0.f, 0.f, 0.f, 0.f};

  const bf16x8* Xv = (const bf16x8*)sh.c.Xl;
  const bf16x8* Wv = (const bf16x8*)sh.c.Wl;
  float* Wf = (float*)sh.c.Wl;

  f32x4 w0v, w1v, w2v;
  {
    const float* src = WS + WB_OFF;
    ld_llc4_nw(src + (size_t)t * 4, w0v);
    ld_llc4_nw(src + (size_t)(t + 512) * 4, w1v);
    ld_llc4_nw(src + (size_t)(t + 1024) * 4, w2v);
  }
  for (int dy = 0; dy < 3; ++dy) {
    llc_wait();                      // this dy's W regs valid
    __syncthreads();                 // prior MFMA done reading Wl
    *(f32x4*)&Wf[(size_t)t * 4] = w0v;
    *(f32x4*)&Wf[(size_t)(t + 512) * 4] = w1v;
    *(f32x4*)&Wf[(size_t)(t + 1024) * 4] = w2v;
    if (dy < 2) {                    // prefetch next dy under this dy's MFMA
      const float* src = WS + WB_OFF + (size_t)(dy + 1) * 6144;
      ld_llc4_nw(src + (size_t)t * 4, w0v);
      ld_llc4_nw(src + (size_t)(t + 512) * 4, w1v);
      ld_llc4_nw(src + (size_t)(t + 1024) * 4, w2v);
    }
    __syncthreads();                 // Wl visible

    #pragma unroll
    for (int dx = 0; dx < 3; ++dx) {
      #pragma unroll
      for (int kh = 0; kh < 2; ++kh) {
        const int kg = kh * 4 + l4;
        bf16x8 afr[2];
        #pragma unroll
        for (int m = 0; m < 2; ++m) {
          const int o = oh * 32 + m * 16 + l15;
          afr[m] = Wv[o * 24 + dx * 8 + (kg ^ (o & 7))];
        }
        const int colp = pg * 16 + l15 + dx;
        const bf16x8 bfr = Xv[((dy * 66 + colp) << 3) + (kg ^ (colp & 7))];
        #pragma unroll
        for (int m = 0; m < 2; ++m)
          acc[m] = __builtin_amdgcn_mfma_f32_16x16x32_bf16(
              afr[m], bfr, acc[m], 0, 0, 0);
      }
    }
  }

  {
    const int px = pg * 16 + l15;
    float* yq = WS + Y_OFF + (((size_t)b * 4096 + r * 64 + px) << 6);
    #pragma unroll
    for (int m = 0; m < 2; ++m)
      stg_llc4(yq + oh * 32 + m * 16 + l4 * 4, acc[m]);
  }

  __syncthreads();
  {
    float* sred = sh.c.part;                // [8 waves][32 o][2]
    #pragma unroll
    for (int m = 0; m < 2; ++m) {
      #pragma unroll
      for (int j = 0; j < 4; ++j) {
        float s1 = acc[m][j];
        float s2 = acc[m][j] * acc[m][j];
        #pragma unroll
        for (int off = 1; off < 16; off <<= 1) {
          s1 += __shfl_xor(s1, off);
          s2 += __shfl_xor(s2, off);
        }
        if (l15 == 0) {
          const int ol = m * 16 + l4 * 4 + j;   // 0..31
          sred[(w * 32 + ol) * 2 + 0] = s1;
          sred[(w * 32 + ol) * 2 + 1] = s2;
        }
      }
    }
    __syncthreads();
    if (t < 128) {
      const int o = t >> 1, wh = t & 1;
      const int ohh = o >> 5, ol = o & 31;
      float s = 0.f;
      #pragma unroll
      for (int pq = 0; pq < 4; ++pq)
        s += sred[(((ohh * 4 + pq) * 32) + ol) * 2 + wh];
      stg_llc1(&WS[P_OFF + (((size_t)b * 64 + r) * 64 + o) * 2 + wh], s);
    }
  }

  // ================= per-b passive barrier (no fences) =================
  asm volatile("s_waitcnt vmcnt(0)" ::: "memory");
  __syncthreads();
  if (t == 0) {
    unsigned* cnt = &bar_cnt[b * 64];
    unsigned* gen = &bar_gen[b * 64];
    const unsigned g0 = ld_llcu(gen);
    const unsigned old = __hip_atomic_fetch_add(cnt, 1u, __ATOMIC_RELAXED,
                                                __HIP_MEMORY_SCOPE_AGENT);
    if (old == 63u) {
      __hip_atomic_store(cnt, 0u, __ATOMIC_RELAXED, __HIP_MEMORY_SCOPE_AGENT);
      __hip_atomic_fetch_add(gen, 1u, __ATOMIC_RELAXED,
                             __HIP_MEMORY_SCOPE_AGENT);
    } else {
      while (ld_llcu(gen) == g0) __builtin_amdgcn_s_sleep(8);
    }
  }
  __syncthreads();

  // ================= Phase B: gout tile (b, ty, tx), 32x32 queries ========
  const int ty = (bid >> 3) & 7;
  const int tx = bid & 7;
  const int cy_base = ty * 8 - 1, cx_base = tx * 8 - 1;
  float* WcL = &sh.g.G[0][0];   // stage Wc+bc here before G overwrites it

  // ---- batched LLC-bypass staging: issue all 11 loads, ONE waitcnt.
  f32x4 pv0, pv1, pv2, pv3, wv0, wv1, wv2, yv[4];
  int ycell[4], ycq[4];
  bool yok[4];
  {
    const float* Pb = WS + P_OFF + (size_t)b * 8192;
    ld_llc4_nw(Pb + (size_t)t * 4, pv0);
    ld_llc4_nw(Pb + (size_t)(t + 512) * 4, pv1);
    ld_llc4_nw(Pb + (size_t)(t + 1024) * 4, pv2);
    ld_llc4_nw(Pb + (size_t)(t + 1536) * 4, pv3);
    ld_llc4_nw(WS + WC_OFF + (size_t)t * 4, wv0);
    ld_llc4_nw(WS + WC_OFF + (size_t)(t + 512) * 4, wv1);
    const int i4 = 1024 + t;
    const float* wp2 = (i4 < 1056) ? (WS + WC_OFF + (size_t)i4 * 4)
                     : (i4 < 1072) ? (WS + BC_OFF + (size_t)(i4 - 1056) * 4)
                                   : (WS + WC_OFF);
    ld_llc4_nw(wp2, wv2);
    const float* yb = WS + Y_OFF + ((size_t)b << 18);
    #pragma unroll
    for (int k = 0; k < 4; ++k) {
      const int f = t + k * 512;
      const int cell = f >> 4, cq = f & 15;
      const int li = cell / 10, lj = cell - li * 10;
      const int ciy = cy_base + li, cix = cx_base + lj;
      const bool ok = (f < 1600) && ciy >= 0 && ciy < 64 && cix >= 0 && cix < 64;
      ycell[k] = cell; ycq[k] = cq; yok[k] = ok;
      const float* ya = ok ? (yb + (((size_t)(ciy << 6) + cix) << 6) + cq * 4) : yb;
      ld_llc4_nw(ya, yv[k]);
    }
    llc_wait();
  }

  // ---- store P partial sums + WcL to LDS
  {
    const f32x4 ps = pv0 + pv1 + pv2 + pv3;
    *(f32x4*)&sh.g.red[(t >> 5) * 128 + (t & 31) * 4] = ps;
    *(f32x4*)&WcL[t * 4] = wv0;
    *(f32x4*)&WcL[(t + 512) * 4] = wv1;
    if (1024 + t < 1072) *(f32x4*)&WcL[(1024 + t) * 4] = wv2;
  }
  __syncthreads();

  // ---- rel-term Wc rows to regs; A,B coefs + bc copy (t<64); WcT bf16 build
  const int sub = t & 3, chb = sub * 16;
  float4 wa[4], wb[4];
  #pragma unroll
  for (int k = 0; k < 4; ++k) {
    wa[k] = *(const float4*)&WcL[64 * 64 + chb + k * 4];
    wb[k] = *(const float4*)&WcL[65 * 64 + chb + k * 4];
  }
  if (t < 64) {
    float S1 = 0.f, S2 = 0.f;
    #pragma unroll
    for (int m = 0; m < 16; ++m) {
      S1 += sh.g.red[m * 128 + t * 2];
      S2 += sh.g.red[m * 128 + t * 2 + 1];
    }
    const float mu = S1 * (1.f / 4096.f);
    const float var = S2 * (1.f / 4096.f) - mu * mu;
    const float dm = ld_llcf(WS + DM_OFF + b * 64 + t);
    const float rstd = rsqrtf(dm * dm * var + 1e-5f);
    const float A = dm * rstd * scale2[b * 64 + t];
    sh.g.A[t] = A;
    sh.g.B[t] = -mu * A + shiftp[b * 64 + t] + act_b[t];
    sh.g.bcl[t] = WcL[4224 + t];
  }
  {
    // WcTb[o][c] = bf16(Wc[c][o]); thread t: o = t>>3, 8 channels (t&7)*8..
    const int o = t >> 3, g = t & 7;
    int4 pk;
    unsigned int e0, e1, e2, e3;
    e0 = (unsigned int)f2bf(WcL[(g * 8 + 0) * 64 + o]) |
         ((unsigned int)f2bf(WcL[(g * 8 + 1) * 64 + o]) << 16);
    e1 = (unsigned int)f2bf(WcL[(g * 8 + 2) * 64 + o]) |
         ((unsigned int)f2bf(WcL[(g * 8 + 3) * 64 + o]) << 16);
    e2 = (unsigned int)f2bf(WcL[(g * 8 + 4) * 64 + o]) |
         ((unsigned int)f2bf(WcL[(g * 8 + 5) * 64 + o]) << 16);
    e3 = (unsigned int)f2bf(WcL[(g * 8 + 6) * 64 + o]) |
         ((unsigned int)f2bf(WcL[(g * 8 + 7) * 64 + o]) << 16);
    pk.x = (int)e0; pk.y = (int)e1; pk.z = (int)e2; pk.w = (int)e3;
    *(int4*)&sh.g.WcTb[o][g * 8] = pk;
  }
  __syncthreads();   // A,B,bcl,WcTb ready; WcL consumed

  // ---- ft: apply affine + leaky to preloaded y values -> bf16 A tile
  {
    const float4* A4 = (const float4*)sh.g.A;
    const float4* B4 = (const float4*)sh.g.B;
    #pragma unroll
    for (int k = 0; k < 4; ++k) {
      if (yok[k]) {
        const float4 Av = A4[ycq[k]], Bv = B4[ycq[k]];
        float f0, f1, f2, f3, u;
        u = yv[k][0] * Av.x + Bv.x; f0 = (u > 0.f ? u : 0.2f * u) * SQRT2F;
        u = yv[k][1] * Av.y + Bv.y; f1 = (u > 0.f ? u : 0.2f * u) * SQRT2F;
        u = yv[k][2] * Av.z + Bv.z; f2 = (u > 0.f ? u : 0.2f * u) * SQRT2F;
        u = yv[k][3] * Av.w + Bv.w; f3 = (u > 0.f ? u : 0.2f * u) * SQRT2F;
        uint2 u2;
        u2.x = (unsigned int)f2bf(f0) | ((unsigned int)f2bf(f1) << 16);
        u2.y = (unsigned int)f2bf(f2) | ((unsigned int)f2bf(f3) << 16);
        *(uint2*)&sh.g.ftb[ycell[k]][ycq[k] * 4] = u2;
      }
    }
  }
  __syncthreads();

  // ---- MFMA G-GEMM: G[cell][o] = bc[o] + ftb[cell][:] @ WcTb[o][:]
  if (w < 7) {
    bf16x8 afr[2];
    #pragma unroll
    for (int kt = 0; kt < 2; ++kt)
      afr[kt] = *(const bf16x8*)&sh.g.ftb[w * 16 + l15][kt * 32 + l4 * 8];
    #pragma unroll
    for (int n = 0; n < 4; ++n) {
      const float bcv = sh.g.bcl[n * 16 + l15];
      f32x4 gacc = (f32x4){bcv, bcv, bcv, bcv};
      #pragma unroll
      for (int kt = 0; kt < 2; ++kt) {
        const bf16x8 bfr =
            *(const bf16x8*)&sh.g.WcTb[n * 16 + l15][kt * 32 + l4 * 8];
        gacc = __builtin_amdgcn_mfma_f32_16x16x32_bf16(afr[kt], bfr, gacc, 0, 0, 0);
      }
      #pragma unroll
      for (int j = 0; j < 4; ++j) {
        const int row = w * 16 + l4 * 4 + j;
        if (row < 100) sh.g.G[row][n * 16 + l15] = gacc[j];
      }
    }
  }
  __syncthreads();

  // ---- 1024 queries, 4 threads/query, 8 passes
  const float lo = -1.f + 1e-6f, hi = 1.f - 1e-6f;
  #pragma unroll 1
  for (int pass = 0; pass < 8; ++pass) {
    const int qi = pass * 128 + (t >> 2);
    const int oy = (ty << 5) + (qi >> 5), ox = (tx << 5) + (qi & 31);

    const float cy0 = -1.f + (2.f * oy + 1.f) * (1.f / 256.f);
    const float cx0 = -1.f + (2.f * ox + 1.f) * (1.f / 256.f);

    int lcell[4];
    float area[4], rely[4], relx[4];
    int j = 0;
    #pragma unroll
    for (int vx = -1; vx <= 1; vx += 2) {
      #pragma unroll
      for (int vy = -1; vy <= 1; vy += 2) {
        float cy = cy0 + (float)vx * (1.f / 64.f) + 1e-6f;
        cy = fminf(fmaxf(cy, lo), hi);
        float cx = cx0 + (float)vy * (1.f / 64.f) + 1e-6f;
        cx = fminf(fmaxf(cx, lo), hi);
        const float fy = floorf((cy + 1.f) * 32.f);
        const float fx = floorf((cx + 1.f) * 32.f);
        const int iy = (int)fminf(fmaxf(fy, 0.f), 63.f);
        const int ix = (int)fminf(fmaxf(fx, 0.f), 63.f);
        const float qy = -1.f + (2.f * iy + 1.f) * (1.f / 64.f);
        const float qx = -1.f + (2.f * ix + 1.f) * (1.f / 64.f);
        const float ry_ = (cy0 - qy) * 64.f;
        const float rx_ = (cx0 - qx) * 64.f;
        lcell[j] = (iy - cy_base) * 10 + (ix - cx_base);
        rely[j] = ry_; relx[j] = rx_;
        area[j] = fabsf(ry_ * rx_) + 1e-9f;
        ++j;
      }
    }
    const float tot = area[0] + area[1] + area[2] + area[3];
    float wgt[4];
    #pragma unroll
    for (int k = 0; k < 4; ++k) wgt[k] = area[3 - k] / tot;   // diagonal swap
    const float swy = wgt[0] * rely[0] + wgt[1] * rely[1] + wgt[2] * rely[2] + wgt[3] * rely[3];
    const float swx = wgt[0] * relx[0] + wgt[1] * relx[1] + wgt[2] * relx[2] + wgt[3] * relx[3];

    float4 rr[4];
    #pragma unroll
    for (int k = 0; k < 4; ++k) {
      rr[k].x = swy * wa[k].x + swx * wb[k].x;
      rr[k].y = swy * wa[k].y + swx * wb[k].y;
      rr[k].z = swy * wa[k].z + swx * wb[k].z;
      rr[k].w = swy * wa[k].w + swx * wb[k].w;
    }
    #pragma unroll
    for (int jj = 0; jj < 4; ++jj) {
      const float4* gp = (const float4*)&sh.g.G[lcell[jj]][chb];
      const float wv = wgt[jj];
      #pragma unroll
      for (int k = 0; k < 4; ++k) {
        const float4 gv = gp[k];
        rr[k].x += wv * gv.x; rr[k].y += wv * gv.y;
        rr[k].z += wv * gv.z; rr[k].w += wv * gv.w;
      }
    }
    const size_t gq = ((size_t)b << 16) + (oy << 8) + ox;
    float4* op = (float4*)(out + (gq << 6) + chb);
    #pragma unroll
    for (int k = 0; k < 4; ++k) op[k] = rr[k];
  }
}

// ---------------------------------------------------------------------------
extern "C" void kernel_launch(void* const* d_in, const int* in_sizes, int n_in,
                              void* d_out, int out_size, void* d_ws, size_t ws_size,
                              hipStream_t stream) {
  (void)in_sizes; (void)n_in; (void)out_size; (void)d_ws; (void)ws_size;
  const float* x      = (const float*)d_in[0];
  const float* scale1 = (const float*)d_in[1];
  const float* scale2 = (const float*)d_in[2];
  const float* shiftp = (const float*)d_in[3];
  const float* mod_w  = (const float*)d_in[4];
  const float* mod_b  = (const float*)d_in[5];
  const float* conv_w = (const float*)d_in[6];
  const float* act_b  = (const float*)d_in[7];
  const float* w1     = (const float*)d_in[8];
  const float* b1     = (const float*)d_in[9];
  const float* w2     = (const float*)d_in[10];
  const float* b2     = (const float*)d_in[11];
  float* out = (float*)d_out;

  hipLaunchKernelGGL(mega_kernel, dim3(256), dim3(512), 0, stream,
                     x, scale1, scale2, shiftp, mod_w, mod_b, conv_w, act_b,
                     b1, w2, b2, w1, out);
}